// Round 1
// baseline (160.364 us; speedup 1.0000x reference)
//
#include <hip/hip_runtime.h>

#define EMBED 128
#define HEADS 8
#define DEPTH 16
#define NB 32
#define LSEQ 4096
#define MROWS (NB * LSEQ)  // 131072 rows

typedef __bf16 bf16x8 __attribute__((ext_vector_type(8)));
typedef float f32x4 __attribute__((ext_vector_type(4)));
typedef float f32x16 __attribute__((ext_vector_type(16)));

__device__ __forceinline__ unsigned short f2bf(float f) {
  unsigned x = __builtin_bit_cast(unsigned, f);
  x += 0x7FFFu + ((x >> 16) & 1u);  // round-to-nearest-even
  return (unsigned short)(x >> 16);
}

union U8 {
  unsigned short s[8];
  unsigned u[4];
  bf16x8 v;
};

// Y[M x 128] = X[M x 128] @ W[128 x 128] + b   (W row-major [in][out])
// Block: 256 threads (4 waves), BM = 128 rows/block. Wave handles 32 rows.
template <bool IN_BF16, bool OUT_BF16>
__global__ __launch_bounds__(256) void gemm128(const void* __restrict__ Xv,
                                               const float* __restrict__ W,
                                               const float* __restrict__ bias,
                                               void* __restrict__ Yv) {
  __shared__ unsigned short Wt[128][136];  // [out][in], +8 pad (2-way bank = free)
  const int tid = threadIdx.x;
#pragma unroll 4
  for (int i = 0; i < 64; ++i) {
    int idx = tid + i * 256;               // idx = in*128 + out
    Wt[idx & 127][idx >> 7] = f2bf(W[idx]);
  }
  __syncthreads();

  const int w = tid >> 6, l = tid & 63;
  const int lr = l & 15, lg = l >> 4;
  const long base = (long)blockIdx.x * 128 + w * 32;

  f32x4 acc[2][8] = {};
#pragma unroll
  for (int ks = 0; ks < 4; ++ks) {
    const int k0 = ks * 32 + lg * 8;
    bf16x8 a[2];
#pragma unroll
    for (int rt = 0; rt < 2; ++rt) {
      const long row = base + rt * 16 + lr;
      if constexpr (IN_BF16) {
        a[rt] = *reinterpret_cast<const bf16x8*>(
            (const unsigned short*)Xv + row * 128 + k0);
      } else {
        const float4* xp = reinterpret_cast<const float4*>(
            (const float*)Xv + row * 128 + k0);
        float4 f0 = xp[0], f1 = xp[1];
        U8 u;
        u.s[0] = f2bf(f0.x); u.s[1] = f2bf(f0.y);
        u.s[2] = f2bf(f0.z); u.s[3] = f2bf(f0.w);
        u.s[4] = f2bf(f1.x); u.s[5] = f2bf(f1.y);
        u.s[6] = f2bf(f1.z); u.s[7] = f2bf(f1.w);
        a[rt] = u.v;
      }
    }
#pragma unroll
    for (int c = 0; c < 8; ++c) {
      bf16x8 bfr = *reinterpret_cast<const bf16x8*>(&Wt[c * 16 + lr][k0]);
      acc[0][c] = __builtin_amdgcn_mfma_f32_16x16x32_bf16(a[0], bfr, acc[0][c], 0, 0, 0);
      acc[1][c] = __builtin_amdgcn_mfma_f32_16x16x32_bf16(a[1], bfr, acc[1][c], 0, 0, 0);
    }
  }

#pragma unroll
  for (int c = 0; c < 8; ++c) {
    const int col = c * 16 + lr;
    const float bv = bias[col];
#pragma unroll
    for (int rt = 0; rt < 2; ++rt) {
#pragma unroll
      for (int j = 0; j < 4; ++j) {
        const long row = base + rt * 16 + lg * 4 + j;
        const float val = acc[rt][c][j] + bv;
        if constexpr (OUT_BF16)
          ((unsigned short*)Yv)[row * 128 + col] = f2bf(val);
        else
          ((float*)Yv)[row * 128 + col] = val;
      }
    }
  }
}

// Batch-axis attention: per (t, h) one wave.
//   S^T[m][n] = sum_d K[m,d] Q[n,d]   via one mfma_32x32x16 (A=K, B=Q)
//   softmax over m (rows of S^T): in-lane over 16 regs + shfl_xor(32)
//   O[n][d]  = sum_m P[n][m] V[m][d]  via 2x mfma_32x32x16 (m halves)
// Writes bf16 in place over q (wave touches only its own (t, h-slice)).
__global__ __launch_bounds__(512) void attn32(const unsigned short* __restrict__ q,
                                              const unsigned short* __restrict__ k,
                                              const unsigned short* __restrict__ v,
                                              unsigned short* __restrict__ o) {
  const int t = blockIdx.x;
  const int h = threadIdx.x >> 6;
  const int l = threadIdx.x & 63;
  const int n32 = l & 31, hi = l >> 5;

  const long off = ((long)n32 * LSEQ + t) * 128 + h * 16 + hi * 8;
  bf16x8 qf = *reinterpret_cast<const bf16x8*>(q + off);
  bf16x8 kf = *reinterpret_cast<const bf16x8*>(k + off);
  f32x16 zz = {};
  f32x16 sT = __builtin_amdgcn_mfma_f32_32x32x16_bf16(kf, qf, zz, 0, 0, 0);
  // lane holds col n = l&31; rows m = (r&3) + 8*(r>>2) + 4*hi for r=0..15

  float mx = sT[0];
#pragma unroll
  for (int r = 1; r < 16; ++r) mx = fmaxf(mx, sT[r]);
  mx = fmaxf(mx, __shfl_xor(mx, 32));
  float p[16], sum = 0.f;
#pragma unroll
  for (int r = 0; r < 16; ++r) {
    p[r] = exp2f((sT[r] - mx) * 1.44269504089f);
    sum += p[r];
  }
  sum += __shfl_xor(sum, 32);
  const float inv = 1.0f / sum;
#pragma unroll
  for (int r = 0; r < 16; ++r) p[r] *= inv;

  const int dl = n32 & 15;  // clamp B cols 16..31 (discarded) onto valid d
  f32x16 Oacc = {};
#pragma unroll
  for (int mh = 0; mh < 2; ++mh) {
    // Rebuild P as A-fragment: lane needs P[n=l&31][m = 16*mh + 8*hi + e].
    // Source reg r = 8*mh + 4*hi_dest + (e&3), source lane-half hi' = e>>2.
    unsigned PaLo = (unsigned)f2bf(p[8 * mh + 0]) | ((unsigned)f2bf(p[8 * mh + 1]) << 16);
    unsigned PbLo = (unsigned)f2bf(p[8 * mh + 2]) | ((unsigned)f2bf(p[8 * mh + 3]) << 16);
    unsigned PaHi = (unsigned)f2bf(p[8 * mh + 4]) | ((unsigned)f2bf(p[8 * mh + 5]) << 16);
    unsigned PbHi = (unsigned)f2bf(p[8 * mh + 6]) | ((unsigned)f2bf(p[8 * mh + 7]) << 16);
    unsigned XaLo = __shfl_xor(PaLo, 32), XbLo = __shfl_xor(PbLo, 32);
    unsigned XaHi = __shfl_xor(PaHi, 32), XbHi = __shfl_xor(PbHi, 32);
    U8 pa;
    pa.u[0] = hi ? XaHi : PaLo;
    pa.u[1] = hi ? XbHi : PbLo;
    pa.u[2] = hi ? PaHi : XaLo;
    pa.u[3] = hi ? PbHi : XbLo;

    U8 vb;  // B-frag: col d = l&31 (clamped), k = 8*hi + e, m = 16*mh + k
#pragma unroll
    for (int e = 0; e < 8; ++e) {
      const int m = mh * 16 + hi * 8 + e;
      vb.s[e] = v[((long)m * LSEQ + t) * 128 + h * 16 + dl];
    }
    Oacc = __builtin_amdgcn_mfma_f32_32x32x16_bf16(pa.v, vb.v, Oacc, 0, 0, 0);
  }

  if (n32 < 16) {  // D cols 0..15 hold d; rows n = (r&3)+8*(r>>2)+4*hi
#pragma unroll
    for (int r = 0; r < 16; ++r) {
      const int n = (r & 3) + 8 * (r >> 2) + 4 * hi;
      o[((long)n * LSEQ + t) * 128 + h * 16 + n32] = f2bf(Oacc[r]);
    }
  }
}

extern "C" void kernel_launch(void* const* d_in, const int* in_sizes, int n_in,
                              void* d_out, int out_size, void* d_ws, size_t ws_size,
                              hipStream_t stream) {
  const float* values  = (const float*)d_in[0];
  const float* keys    = (const float*)d_in[1];
  const float* queries = (const float*)d_in[2];
  const float* Wv = (const float*)d_in[3];
  const float* bv = (const float*)d_in[4];
  const float* Wk = (const float*)d_in[5];
  const float* bk = (const float*)d_in[6];
  const float* Wq = (const float*)d_in[7];
  const float* bq = (const float*)d_in[8];
  const float* Wo = (const float*)d_in[9];
  const float* bo = (const float*)d_in[10];

  unsigned short* qws = (unsigned short*)d_ws;                 // 32 MB
  unsigned short* kws = qws + (size_t)MROWS * 128;             // 32 MB
  unsigned short* vws = kws + (size_t)MROWS * 128;             // 32 MB

  dim3 gb(256), gg(MROWS / 128);
  gemm128<false, true><<<gg, gb, 0, stream>>>(queries, Wq, bq, qws);
  gemm128<false, true><<<gg, gb, 0, stream>>>(keys, Wk, bk, kws);
  gemm128<false, true><<<gg, gb, 0, stream>>>(values, Wv, bv, vws);
  attn32<<<dim3(LSEQ), dim3(512), 0, stream>>>(qws, kws, vws, qws);
  gemm128<true, false><<<gg, gb, 0, stream>>>(qws, Wo, bo, (float*)d_out);
}

// Round 2
// 107.818 us; speedup vs baseline: 1.4874x; 1.4874x over previous
//
#include <hip/hip_runtime.h>

#define LSEQ 4096

typedef __bf16 bf16x8 __attribute__((ext_vector_type(8)));
typedef float f32x16 __attribute__((ext_vector_type(16)));

union FU { unsigned u[4]; uint4 u4; bf16x8 v; };

__device__ __forceinline__ unsigned short bfb(float f) {
  __bf16 h = (__bf16)f;
  return __builtin_bit_cast(unsigned short, h);
}
__device__ __forceinline__ unsigned pk2(float a, float b) {
  return (unsigned)bfb(a) | ((unsigned)bfb(b) << 16);
}

// Universal half-exchange (generalizes the verified round-0 P-rebuild):
// P0..P3 are bf16-pair packs; returns the 4 u32 of a bf16x8 A/B-fragment.
__device__ __forceinline__ void xchg(unsigned P0, unsigned P1, unsigned P2, unsigned P3,
                                     const int hi, unsigned o[4]) {
  const unsigned sA = hi ? P0 : P2, sB = hi ? P1 : P3;
  const unsigned rA = __shfl_xor(sA, 32), rB = __shfl_xor(sB, 32);
  o[0] = hi ? rA : P0; o[1] = hi ? rB : P1;
  o[2] = hi ? P2 : rA; o[3] = hi ? P3 : rB;
}

// One wave per sequence position t (x2 per wave). All four 128x128 weights
// (+bias as a 9th K-step) staged in LDS in exact MFMA-fragment order:
// wlds[w][nt][ks][lane][e] ; frag read = ds_read_b128 at base + lane*16.
__global__ __launch_bounds__(512) void fused_mha(
    const float* __restrict__ Xv, const float* __restrict__ Xk, const float* __restrict__ Xq,
    const float* __restrict__ Wv, const float* __restrict__ bv,
    const float* __restrict__ Wk, const float* __restrict__ bk,
    const float* __restrict__ Wq, const float* __restrict__ bq,
    const float* __restrict__ Wo, const float* __restrict__ bo,
    float* __restrict__ out) {
  __shared__ unsigned short wlds[73728];  // 4*4*9*64*8 = 144 KB
  const int tid = threadIdx.x;
  {
    const float* Wp[4] = {Wv, Wk, Wq, Wo};
#pragma unroll
    for (int w = 0; w < 4; ++w) {
      for (int idx = tid; idx < 4096; idx += 512) {
        const int k = idx >> 5, j4 = (idx & 31) << 2;
        const float4 f = *reinterpret_cast<const float4*>(Wp[w] + k * 128 + j4);
        const int ks = k >> 4, h2 = (k >> 3) & 1, e = k & 7;
        const float ff[4] = {f.x, f.y, f.z, f.w};
#pragma unroll
        for (int jj = 0; jj < 4; ++jj) {
          const int j = j4 + jj;
          wlds[((((w * 4 + (j >> 5)) * 9 + ks) * 64 + ((h2 << 5) | (j & 31))) << 3) + e] =
              bfb(ff[jj]);
        }
      }
    }
    const float* Bp[4] = {bv, bk, bq, bo};
    for (int idx = tid; idx < 1024; idx += 512) {
      const int w = idx >> 8, nt = (idx >> 6) & 3, lane = idx & 63;
      const int base = (((w * 4 + nt) * 9 + 8) * 64 + lane) << 3;
      wlds[base] = (lane < 32) ? bfb(Bp[w][nt * 32 + lane]) : (unsigned short)0;
#pragma unroll
      for (int e = 1; e < 8; ++e) wlds[base + e] = 0;
    }
  }
  __syncthreads();

  const uint4* wl4 = reinterpret_cast<const uint4*>(wlds);
  const int wid = tid >> 6, l = tid & 63;
  const int l31 = l & 31, hi = l >> 5;
  FU cf;  // X-extension constant frag (bias K-step): 1.0 at k-offset 0
  cf.u[0] = hi ? 0u : 0x00003F80u; cf.u[1] = 0; cf.u[2] = 0; cf.u[3] = 0;

#pragma unroll 1
  for (int it = 0; it < 2; ++it) {
    const int t = (blockIdx.x << 4) + (wid << 1) + it;

    FU xf[8];
    f32x16 acc[4];
    FU kf[8], qf[8];
    unsigned vpk[4][8];

    // ---------- K projection (option B: D = K^T tiles), w=1 ----------
    {
      const float* bp = Xk + ((long)l31 * LSEQ + t) * 128 + (hi << 3);
#pragma unroll
      for (int ks = 0; ks < 8; ++ks) {
        const float4 a = *reinterpret_cast<const float4*>(bp + ks * 16);
        const float4 b = *reinterpret_cast<const float4*>(bp + ks * 16 + 4);
        xf[ks].u[0] = pk2(a.x, a.y); xf[ks].u[1] = pk2(a.z, a.w);
        xf[ks].u[2] = pk2(b.x, b.y); xf[ks].u[3] = pk2(b.z, b.w);
      }
#pragma unroll
      for (int nt = 0; nt < 4; ++nt) acc[nt] = (f32x16){};
#pragma unroll
      for (int ks = 0; ks < 8; ++ks)
#pragma unroll
        for (int nt = 0; nt < 4; ++nt) {
          FU wf; wf.u4 = wl4[((4 + nt) * 9 + ks) * 64 + l];
          acc[nt] = __builtin_amdgcn_mfma_f32_32x32x16_bf16(wf.v, xf[ks].v, acc[nt], 0, 0, 0);
        }
#pragma unroll
      for (int nt = 0; nt < 4; ++nt) {
        FU wf; wf.u4 = wl4[((4 + nt) * 9 + 8) * 64 + l];
        acc[nt] = __builtin_amdgcn_mfma_f32_32x32x16_bf16(wf.v, cf.v, acc[nt], 0, 0, 0);
      }
#pragma unroll
      for (int h = 0; h < 8; ++h) {
        const int nt = h >> 1, c8 = (h & 1) << 3;
        xchg(pk2(acc[nt][c8 + 0], acc[nt][c8 + 1]), pk2(acc[nt][c8 + 2], acc[nt][c8 + 3]),
             pk2(acc[nt][c8 + 4], acc[nt][c8 + 5]), pk2(acc[nt][c8 + 6], acc[nt][c8 + 7]),
             hi, kf[h].u);
      }
    }

    // ---------- Q projection (option B), w=2 ----------
    {
      const float* bp = Xq + ((long)l31 * LSEQ + t) * 128 + (hi << 3);
#pragma unroll
      for (int ks = 0; ks < 8; ++ks) {
        const float4 a = *reinterpret_cast<const float4*>(bp + ks * 16);
        const float4 b = *reinterpret_cast<const float4*>(bp + ks * 16 + 4);
        xf[ks].u[0] = pk2(a.x, a.y); xf[ks].u[1] = pk2(a.z, a.w);
        xf[ks].u[2] = pk2(b.x, b.y); xf[ks].u[3] = pk2(b.z, b.w);
      }
#pragma unroll
      for (int nt = 0; nt < 4; ++nt) acc[nt] = (f32x16){};
#pragma unroll
      for (int ks = 0; ks < 8; ++ks)
#pragma unroll
        for (int nt = 0; nt < 4; ++nt) {
          FU wf; wf.u4 = wl4[((8 + nt) * 9 + ks) * 64 + l];
          acc[nt] = __builtin_amdgcn_mfma_f32_32x32x16_bf16(wf.v, xf[ks].v, acc[nt], 0, 0, 0);
        }
#pragma unroll
      for (int nt = 0; nt < 4; ++nt) {
        FU wf; wf.u4 = wl4[((8 + nt) * 9 + 8) * 64 + l];
        acc[nt] = __builtin_amdgcn_mfma_f32_32x32x16_bf16(wf.v, cf.v, acc[nt], 0, 0, 0);
      }
#pragma unroll
      for (int h = 0; h < 8; ++h) {
        const int nt = h >> 1, c8 = (h & 1) << 3;
        xchg(pk2(acc[nt][c8 + 0], acc[nt][c8 + 1]), pk2(acc[nt][c8 + 2], acc[nt][c8 + 3]),
             pk2(acc[nt][c8 + 4], acc[nt][c8 + 5]), pk2(acc[nt][c8 + 6], acc[nt][c8 + 7]),
             hi, qf[h].u);
      }
    }

    // ---------- V projection (option A: D = V tiles), w=0 ----------
    {
      const float* bp = Xv + ((long)l31 * LSEQ + t) * 128 + (hi << 3);
#pragma unroll
      for (int ks = 0; ks < 8; ++ks) {
        const float4 a = *reinterpret_cast<const float4*>(bp + ks * 16);
        const float4 b = *reinterpret_cast<const float4*>(bp + ks * 16 + 4);
        xf[ks].u[0] = pk2(a.x, a.y); xf[ks].u[1] = pk2(a.z, a.w);
        xf[ks].u[2] = pk2(b.x, b.y); xf[ks].u[3] = pk2(b.z, b.w);
      }
#pragma unroll
      for (int nt = 0; nt < 4; ++nt) acc[nt] = (f32x16){};
#pragma unroll
      for (int ks = 0; ks < 8; ++ks)
#pragma unroll
        for (int nt = 0; nt < 4; ++nt) {
          FU wf; wf.u4 = wl4[(nt * 9 + ks) * 64 + l];
          acc[nt] = __builtin_amdgcn_mfma_f32_32x32x16_bf16(xf[ks].v, wf.v, acc[nt], 0, 0, 0);
        }
#pragma unroll
      for (int nt = 0; nt < 4; ++nt) {
        FU wf; wf.u4 = wl4[(nt * 9 + 8) * 64 + l];
        acc[nt] = __builtin_amdgcn_mfma_f32_32x32x16_bf16(cf.v, wf.v, acc[nt], 0, 0, 0);
      }
#pragma unroll
      for (int nt = 0; nt < 4; ++nt)
#pragma unroll
        for (int jv = 0; jv < 8; ++jv)
          vpk[nt][jv] = pk2(acc[nt][2 * jv], acc[nt][2 * jv + 1]);
    }

    // ---------- attention over the batch axis + output fragments ----------
    FU ofr[8];
#pragma unroll
    for (int nt = 0; nt < 4; ++nt) {
      FU vm0, vm1, vs0, vs1;
      xchg(vpk[nt][0], vpk[nt][1], vpk[nt][2], vpk[nt][3], hi, vm0.u);
      xchg(vpk[nt][4], vpk[nt][5], vpk[nt][6], vpk[nt][7], hi, vm1.u);
#pragma unroll
      for (int i = 0; i < 4; ++i) {
        vs0.u[i] = __shfl_xor(vm0.u[i], 16);
        vs1.u[i] = __shfl_xor(vm1.u[i], 16);
      }
#pragma unroll
      for (int ch = 0; ch < 2; ++ch) {
        const int h = nt * 2 + ch;
        const bool own = ((l31 >> 4) == ch);
        f32x16 zz = {};
        f32x16 S = __builtin_amdgcn_mfma_f32_32x32x16_bf16(kf[h].v, qf[h].v, zz, 0, 0, 0);
        float mx = S[0];
#pragma unroll
        for (int r = 1; r < 16; ++r) mx = fmaxf(mx, S[r]);
        mx = fmaxf(mx, __shfl_xor(mx, 32));
        float p[16], sum = 0.f;
#pragma unroll
        for (int r = 0; r < 16; ++r) {
          p[r] = exp2f((S[r] - mx) * 1.44269504089f);
          sum += p[r];
        }
        sum += __shfl_xor(sum, 32);
        const float inv = 1.0f / sum;
        FU pf0, pf1;
        xchg(pk2(p[0], p[1]), pk2(p[2], p[3]), pk2(p[4], p[5]), pk2(p[6], p[7]), hi, pf0.u);
        xchg(pk2(p[8], p[9]), pk2(p[10], p[11]), pk2(p[12], p[13]), pk2(p[14], p[15]), hi, pf1.u);
        FU v0, v1;
#pragma unroll
        for (int i = 0; i < 4; ++i) {
          v0.u[i] = own ? vm0.u[i] : vs0.u[i];
          v1.u[i] = own ? vm1.u[i] : vs1.u[i];
        }
        f32x16 z2 = {};
        f32x16 Ot = __builtin_amdgcn_mfma_f32_32x32x16_bf16(v0.v, pf0.v, z2, 0, 0, 0);
        Ot = __builtin_amdgcn_mfma_f32_32x32x16_bf16(v1.v, pf1.v, Ot, 0, 0, 0);
        xchg(pk2(Ot[0] * inv, Ot[1] * inv), pk2(Ot[2] * inv, Ot[3] * inv),
             pk2(Ot[4] * inv, Ot[5] * inv), pk2(Ot[6] * inv, Ot[7] * inv), hi, ofr[h].u);
      }
    }

    // ---------- output projection (option A), w=3 ----------
#pragma unroll
    for (int nt = 0; nt < 4; ++nt) {
      FU wf8; wf8.u4 = wl4[((12 + nt) * 9 + 8) * 64 + l];
      f32x16 zz = {};
      f32x16 oacc = __builtin_amdgcn_mfma_f32_32x32x16_bf16(cf.v, wf8.v, zz, 0, 0, 0);
#pragma unroll
      for (int h = 0; h < 8; ++h) {
        FU wf; wf.u4 = wl4[((12 + nt) * 9 + h) * 64 + l];
        oacc = __builtin_amdgcn_mfma_f32_32x32x16_bf16(ofr[h].v, wf.v, oacc, 0, 0, 0);
      }
#pragma unroll
      for (int r = 0; r < 16; ++r) {
        const int n = (r & 3) + ((r >> 2) << 3) + (hi << 2);
        out[((long)n * LSEQ + t) * 128 + nt * 32 + l31] = oacc[r];
      }
    }
  }
}

extern "C" void kernel_launch(void* const* d_in, const int* in_sizes, int n_in,
                              void* d_out, int out_size, void* d_ws, size_t ws_size,
                              hipStream_t stream) {
  const float* values  = (const float*)d_in[0];
  const float* keys    = (const float*)d_in[1];
  const float* queries = (const float*)d_in[2];
  const float* Wv = (const float*)d_in[3];
  const float* bv = (const float*)d_in[4];
  const float* Wk = (const float*)d_in[5];
  const float* bk = (const float*)d_in[6];
  const float* Wq = (const float*)d_in[7];
  const float* bq = (const float*)d_in[8];
  const float* Wo = (const float*)d_in[9];
  const float* bo = (const float*)d_in[10];

  fused_mha<<<dim3(256), dim3(512), 0, stream>>>(
      values, keys, queries, Wv, bv, Wk, bk, Wq, bq, Wo, bo, (float*)d_out);
}

// Round 3
// 64.642 us; speedup vs baseline: 2.4808x; 1.6679x over previous
//
#include <hip/hip_runtime.h>

#define LSEQ 4096

typedef __bf16 bf16x8 __attribute__((ext_vector_type(8)));
typedef float f32x16 __attribute__((ext_vector_type(16)));

union FU { unsigned u[4]; uint4 u4; bf16x8 v; };

__device__ __forceinline__ unsigned short bfb(float f) {
  __bf16 h = (__bf16)f;
  return __builtin_bit_cast(unsigned short, h);
}
__device__ __forceinline__ unsigned pk2(float a, float b) {
  return (unsigned)bfb(a) | ((unsigned)bfb(b) << 16);
}
// Half-exchange across lane 32 boundary (verified in rounds 0-2).
__device__ __forceinline__ void xchg(unsigned P0, unsigned P1, unsigned P2, unsigned P3,
                                     const int hi, unsigned o[4]) {
  const unsigned sA = hi ? P0 : P2, sB = hi ? P1 : P3;
  const unsigned rA = __shfl_xor(sA, 32), rB = __shfl_xor(sB, 32);
  o[0] = hi ? rA : P0; o[1] = hi ? rB : P1;
  o[2] = hi ? P2 : rA; o[3] = hi ? P3 : rB;
}

// Repack weights to fragment order in ws: frag[((m*4+nt)*9+ks)*64 + lane],
// frag[l][e] = W[ks*16 + 8*(l>>5) + e][nt*32 + (l&31)]; ks==8 is the bias
// outer-product fragment (bias at k-offset 0).
__global__ __launch_bounds__(64) void repack(
    const float* __restrict__ Wv, const float* __restrict__ bv,
    const float* __restrict__ Wk, const float* __restrict__ bk,
    const float* __restrict__ Wq, const float* __restrict__ bq,
    const float* __restrict__ Wo, const float* __restrict__ bo,
    uint4* __restrict__ ws) {
  const int b = blockIdx.x;  // 144 = 4 mats * 4 nt * 9 ks
  const int ks = b % 9, nt = (b / 9) & 3, m = b / 36;
  const float* Ws[4] = {Wv, Wk, Wq, Wo};
  const float* Bs[4] = {bv, bk, bq, bo};
  const int l = threadIdx.x, l31 = l & 31, hi = l >> 5;
  FU f;
  if (ks < 8) {
#pragma unroll
    for (int e = 0; e < 4; ++e) {
      const float a = Ws[m][(ks * 16 + hi * 8 + 2 * e) * 128 + nt * 32 + l31];
      const float c = Ws[m][(ks * 16 + hi * 8 + 2 * e + 1) * 128 + nt * 32 + l31];
      f.u[e] = pk2(a, c);
    }
  } else {
    f.u[0] = (hi == 0) ? (unsigned)bfb(Bs[m][nt * 32 + l31]) : 0u;
    f.u[1] = 0; f.u[2] = 0; f.u[3] = 0;
  }
  ws[b * 64 + l] = f.u4;
}

// One t per block. 4 waves; wave nt owns output cols [nt*32, nt*32+32)
// (= heads 2nt, 2nt+1). X staged in LDS (XOR-swizzled fragment layout);
// weights read per-fragment from L2 (ws); head outputs exchanged via LDS.
__global__ __launch_bounds__(256, 4) void fused_mha(
    const float* __restrict__ Xv, const float* __restrict__ Xk, const float* __restrict__ Xq,
    const uint4* __restrict__ wf4, float* __restrict__ out) {
  __shared__ uint4 xlds[3 * 8 * 64];  // 24KB: [tau][ks][lane^ks]
  __shared__ uint4 olds[8 * 64];      // 8KB:  [h][lane]
  const int tid = threadIdx.x;
  const int t = blockIdx.x;

  {  // cooperative X stage: thread = (row r, k-chunk ksc), 64B contiguous
    const int r = tid >> 3, ksc = tid & 7;
    const float* Xs[3] = {Xv, Xk, Xq};
#pragma unroll
    for (int tau = 0; tau < 3; ++tau) {
      const float4* p4 = reinterpret_cast<const float4*>(
          Xs[tau] + ((long)r * LSEQ + t) * 128 + ksc * 16);
      const float4 a = p4[0], b = p4[1], c = p4[2], d = p4[3];
      FU lo, hb;
      lo.u[0] = pk2(a.x, a.y); lo.u[1] = pk2(a.z, a.w);
      lo.u[2] = pk2(b.x, b.y); lo.u[3] = pk2(b.z, b.w);
      hb.u[0] = pk2(c.x, c.y); hb.u[1] = pk2(c.z, c.w);
      hb.u[2] = pk2(d.x, d.y); hb.u[3] = pk2(d.z, d.w);
      xlds[(tau * 8 + ksc) * 64 + (r ^ ksc)] = lo.u4;         // hi=0 half
      xlds[(tau * 8 + ksc) * 64 + ((r ^ ksc) | 32)] = hb.u4;  // hi=1 half
    }
  }
  __syncthreads();

  const int wid = tid >> 6, l = tid & 63;
  const int nt = wid, l31 = l & 31, hi = l >> 5;
  FU cf;  // constant frag: 1.0 at k-offset 0 (bias K-step)
  cf.u[0] = hi ? 0u : 0x00003F80u; cf.u[1] = 0; cf.u[2] = 0; cf.u[3] = 0;

  unsigned vpk[8];
  FU kf[2], qf[2];

  {  // ---- V projection (option A: acc = X@Wv tile), mat 0 ----
    f32x16 acc = {};
#pragma unroll
    for (int ks = 0; ks < 8; ++ks) {
      FU xf; xf.u4 = xlds[(0 * 8 + ks) * 64 + (l ^ ks)];
      FU wf; wf.u4 = wf4[((0 * 4 + nt) * 9 + ks) * 64 + l];
      acc = __builtin_amdgcn_mfma_f32_32x32x16_bf16(xf.v, wf.v, acc, 0, 0, 0);
    }
    FU wb; wb.u4 = wf4[((0 * 4 + nt) * 9 + 8) * 64 + l];
    acc = __builtin_amdgcn_mfma_f32_32x32x16_bf16(cf.v, wb.v, acc, 0, 0, 0);
#pragma unroll
    for (int jv = 0; jv < 8; ++jv) vpk[jv] = pk2(acc[2 * jv], acc[2 * jv + 1]);
  }
  {  // ---- K projection (option B: acc = (Wk tile)^T @ X^T -> K^T), mat 1 ----
    f32x16 acc = {};
#pragma unroll
    for (int ks = 0; ks < 8; ++ks) {
      FU xf; xf.u4 = xlds[(1 * 8 + ks) * 64 + (l ^ ks)];
      FU wf; wf.u4 = wf4[((1 * 4 + nt) * 9 + ks) * 64 + l];
      acc = __builtin_amdgcn_mfma_f32_32x32x16_bf16(wf.v, xf.v, acc, 0, 0, 0);
    }
    FU wb; wb.u4 = wf4[((1 * 4 + nt) * 9 + 8) * 64 + l];
    acc = __builtin_amdgcn_mfma_f32_32x32x16_bf16(wb.v, cf.v, acc, 0, 0, 0);
#pragma unroll
    for (int ch = 0; ch < 2; ++ch) {
      const int c8 = ch * 8;
      xchg(pk2(acc[c8 + 0], acc[c8 + 1]), pk2(acc[c8 + 2], acc[c8 + 3]),
           pk2(acc[c8 + 4], acc[c8 + 5]), pk2(acc[c8 + 6], acc[c8 + 7]), hi, kf[ch].u);
    }
  }
  {  // ---- Q projection (option B), mat 2 ----
    f32x16 acc = {};
#pragma unroll
    for (int ks = 0; ks < 8; ++ks) {
      FU xf; xf.u4 = xlds[(2 * 8 + ks) * 64 + (l ^ ks)];
      FU wf; wf.u4 = wf4[((2 * 4 + nt) * 9 + ks) * 64 + l];
      acc = __builtin_amdgcn_mfma_f32_32x32x16_bf16(wf.v, xf.v, acc, 0, 0, 0);
    }
    FU wb; wb.u4 = wf4[((2 * 4 + nt) * 9 + 8) * 64 + l];
    acc = __builtin_amdgcn_mfma_f32_32x32x16_bf16(wb.v, cf.v, acc, 0, 0, 0);
#pragma unroll
    for (int ch = 0; ch < 2; ++ch) {
      const int c8 = ch * 8;
      xchg(pk2(acc[c8 + 0], acc[c8 + 1]), pk2(acc[c8 + 2], acc[c8 + 3]),
           pk2(acc[c8 + 4], acc[c8 + 5]), pk2(acc[c8 + 6], acc[c8 + 7]), hi, qf[ch].u);
    }
  }

  {  // ---- batch-axis attention for heads 2nt, 2nt+1 ----
    FU vm0, vm1, vs0, vs1;
    xchg(vpk[0], vpk[1], vpk[2], vpk[3], hi, vm0.u);
    xchg(vpk[4], vpk[5], vpk[6], vpk[7], hi, vm1.u);
#pragma unroll
    for (int i = 0; i < 4; ++i) {
      vs0.u[i] = __shfl_xor(vm0.u[i], 16);
      vs1.u[i] = __shfl_xor(vm1.u[i], 16);
    }
#pragma unroll
    for (int ch = 0; ch < 2; ++ch) {
      const int h = nt * 2 + ch;
      const bool own = ((l31 >> 4) == ch);
      f32x16 zz = {};
      f32x16 S = __builtin_amdgcn_mfma_f32_32x32x16_bf16(kf[ch].v, qf[ch].v, zz, 0, 0, 0);
      float mx = S[0];
#pragma unroll
      for (int r = 1; r < 16; ++r) mx = fmaxf(mx, S[r]);
      mx = fmaxf(mx, __shfl_xor(mx, 32));
      float p[16], sum = 0.f;
#pragma unroll
      for (int r = 0; r < 16; ++r) {
        p[r] = exp2f((S[r] - mx) * 1.44269504089f);
        sum += p[r];
      }
      sum += __shfl_xor(sum, 32);
      const float inv = 1.0f / sum;
      FU pf0, pf1;
      xchg(pk2(p[0], p[1]), pk2(p[2], p[3]), pk2(p[4], p[5]), pk2(p[6], p[7]), hi, pf0.u);
      xchg(pk2(p[8], p[9]), pk2(p[10], p[11]), pk2(p[12], p[13]), pk2(p[14], p[15]), hi, pf1.u);
      FU v0, v1;
#pragma unroll
      for (int i = 0; i < 4; ++i) {
        v0.u[i] = own ? vm0.u[i] : vs0.u[i];
        v1.u[i] = own ? vm1.u[i] : vs1.u[i];
      }
      f32x16 z2 = {};
      f32x16 Ot = __builtin_amdgcn_mfma_f32_32x32x16_bf16(v0.v, pf0.v, z2, 0, 0, 0);
      Ot = __builtin_amdgcn_mfma_f32_32x32x16_bf16(v1.v, pf1.v, Ot, 0, 0, 0);
      FU ofr;
      xchg(pk2(Ot[0] * inv, Ot[1] * inv), pk2(Ot[2] * inv, Ot[3] * inv),
           pk2(Ot[4] * inv, Ot[5] * inv), pk2(Ot[6] * inv, Ot[7] * inv), hi, ofr.u);
      olds[h * 64 + l] = ofr.u4;
    }
  }
  __syncthreads();

  {  // ---- output projection (option A over 8 head K-steps), mat 3 ----
    f32x16 acc = {};
#pragma unroll
    for (int h = 0; h < 8; ++h) {
      FU of; of.u4 = olds[h * 64 + l];
      FU wf; wf.u4 = wf4[((3 * 4 + nt) * 9 + h) * 64 + l];
      acc = __builtin_amdgcn_mfma_f32_32x32x16_bf16(of.v, wf.v, acc, 0, 0, 0);
    }
    FU wb; wb.u4 = wf4[((3 * 4 + nt) * 9 + 8) * 64 + l];
    acc = __builtin_amdgcn_mfma_f32_32x32x16_bf16(cf.v, wb.v, acc, 0, 0, 0);
#pragma unroll
    for (int r = 0; r < 16; ++r) {
      const int n = (r & 3) + ((r >> 2) << 3) + (hi << 2);
      out[((long)n * LSEQ + t) * 128 + nt * 32 + l31] = acc[r];
    }
  }
}

extern "C" void kernel_launch(void* const* d_in, const int* in_sizes, int n_in,
                              void* d_out, int out_size, void* d_ws, size_t ws_size,
                              hipStream_t stream) {
  const float* values  = (const float*)d_in[0];
  const float* keys    = (const float*)d_in[1];
  const float* queries = (const float*)d_in[2];
  const float* Wv = (const float*)d_in[3];
  const float* bv = (const float*)d_in[4];
  const float* Wk = (const float*)d_in[5];
  const float* bk = (const float*)d_in[6];
  const float* Wq = (const float*)d_in[7];
  const float* bq = (const float*)d_in[8];
  const float* Wo = (const float*)d_in[9];
  const float* bo = (const float*)d_in[10];

  repack<<<dim3(144), dim3(64), 0, stream>>>(Wv, bv, Wk, bk, Wq, bq, Wo, bo,
                                             (uint4*)d_ws);
  fused_mha<<<dim3(LSEQ), dim3(256), 0, stream>>>(
      values, keys, queries, (const uint4*)d_ws, (float*)d_out);
}